// Round 1
// baseline (35.371 us; speedup 1.0000x reference)
//
#include <hip/hip_runtime.h>
#include <math.h>

// ---------------------------------------------------------------------------
// Problem: B=32768 segments, E=1M sorted edges, DIM=64.
//   score[e]   = dot(H_emb[h[seg[e]]], R_emb[rel[e]])          (table lookup)
//   w          = segment_softmax(score)
//   contrib[e] = w[e] * (tsum[tail[e]] - rsum[rel[e]])
//   out[s][:]  = broadcast(segment_sum(contrib))
// ---------------------------------------------------------------------------

__global__ __launch_bounds__(256) void precompute_k(
    const float* __restrict__ H, const float* __restrict__ R,
    const float* __restrict__ T,
    float* __restrict__ S, float* __restrict__ tsum, float* __restrict__ rsum,
    int NH, int NR, int NT, int sBlocks, int tBlocks)
{
    int b = blockIdx.x;
    if (b < sBlocks) {
        // Score table: S[i*NR + r] = dot64(H[i], R[r])
        int idx = b * 256 + threadIdx.x;
        if (idx < NH * NR) {
            int i = idx / NR;
            int r = idx - i * NR;
            const float* hrow = H + (size_t)i * 64;
            const float* rrow = R + (size_t)r * 64;
            float acc = 0.f;
            #pragma unroll
            for (int d = 0; d < 64; ++d) acc = fmaf(hrow[d], rrow[d], acc);
            S[idx] = acc;
        }
    } else if (b < sBlocks + tBlocks) {
        // tsum[t] = sum_d T[t][d]  (one wave per row)
        int row  = (b - sBlocks) * 4 + (threadIdx.x >> 6);
        int lane = threadIdx.x & 63;
        if (row < NT) {
            float v = T[(size_t)row * 64 + lane];
            #pragma unroll
            for (int off = 32; off; off >>= 1) v += __shfl_xor(v, off, 64);
            if (lane == 0) tsum[row] = v;
        }
    } else {
        // rsum[r] = sum_d R[r][d]
        int row  = (b - sBlocks - tBlocks) * 4 + (threadIdx.x >> 6);
        int lane = threadIdx.x & 63;
        if (row < NR) {
            float v = R[(size_t)row * 64 + lane];
            #pragma unroll
            for (int off = 32; off; off >>= 1) v += __shfl_xor(v, off, 64);
            if (lane == 0) rsum[row] = v;
        }
    }
}

// edge_seg is sorted: seg_start[s] = lower_bound(edge_seg, s), seg_start[B] = E
__global__ __launch_bounds__(256) void seg_bounds_k(
    const int* __restrict__ seg, int E, int B, int* __restrict__ seg_start)
{
    int s = blockIdx.x * 256 + threadIdx.x;
    if (s > B) return;
    int lo = 0, hi = E;
    while (lo < hi) {
        int mid = (lo + hi) >> 1;
        if (seg[mid] < s) lo = mid + 1; else hi = mid;
    }
    seg_start[s] = lo;
}

// One wave per segment: online softmax across the wave's strided edges,
// then a 6-step xor-shuffle merge of (m, sum_e, sum_ec).
__global__ __launch_bounds__(256) void main_k(
    const int* __restrict__ h,
    const int* __restrict__ edge_rel, const int* __restrict__ edge_tail,
    const float* __restrict__ S, const float* __restrict__ tsum,
    const float* __restrict__ rsum, const int* __restrict__ seg_start,
    float* __restrict__ out, int B, int NR)
{
    int wave = blockIdx.x * 4 + (threadIdx.x >> 6);
    int lane = threadIdx.x & 63;
    if (wave >= B) return;

    int lo = seg_start[wave];
    int hi = seg_start[wave + 1];
    int hh = h[wave];
    const float* Srow = S + (size_t)hh * NR;

    // Per-lane online softmax accumulation.
    float m = -INFINITY, se = 0.f, sec = 0.f;
    for (int e = lo + lane; e < hi; e += 64) {
        int rel = edge_rel[e];
        int tl  = edge_tail[e];
        float sc = Srow[rel];
        float c  = tsum[tl] - rsum[rel];
        if (sc > m) {
            float f = __expf(m - sc);   // m=-inf -> f=0 on first hit
            se *= f; sec *= f; m = sc;
        }
        float w = __expf(sc - m);
        se += w; sec = fmaf(w, c, sec);
    }

    // Cross-lane merge (guard empty lanes: se==0 -> scale 0, avoids inf-inf NaN).
    #pragma unroll
    for (int off = 32; off; off >>= 1) {
        float m2   = __shfl_xor(m, off, 64);
        float se2  = __shfl_xor(se, off, 64);
        float sec2 = __shfl_xor(sec, off, 64);
        float M  = fmaxf(m, m2);
        float a  = (se  > 0.f) ? __expf(m  - M) : 0.f;
        float b2 = (se2 > 0.f) ? __expf(m2 - M) : 0.f;
        se  = se * a + se2 * b2;
        sec = sec * a + sec2 * b2;
        m = M;
    }

    float vc = (se > 0.f) ? (sec / se) : 0.f;
    out[(size_t)wave * 64 + lane] = vc;   // broadcast row, coalesced per block
}

extern "C" void kernel_launch(void* const* d_in, const int* in_sizes, int n_in,
                              void* d_out, int out_size, void* d_ws, size_t ws_size,
                              hipStream_t stream)
{
    const int*   h     = (const int*)d_in[0];
    const int*   eseg  = (const int*)d_in[1];
    const int*   erel  = (const int*)d_in[2];
    const int*   etail = (const int*)d_in[3];
    const float* Hv    = (const float*)d_in[4];
    const float* Rv    = (const float*)d_in[5];
    const float* Tv    = (const float*)d_in[6];

    int B  = in_sizes[0];
    int E  = in_sizes[1];
    int NH = in_sizes[4] / 64;
    int NR = in_sizes[5] / 64;
    int NT = in_sizes[6] / 64;

    // Workspace carve-out (256B aligned): seg_start | S | tsum | rsum  (~1.1 MB)
    char*  ws  = (char*)d_ws;
    size_t off = 0;
    auto alloc = [&](size_t bytes) -> void* {
        void* p = ws + off;
        off = (off + bytes + 255) & ~(size_t)255;
        return p;
    };
    int*   seg_start = (int*)  alloc((size_t)(B + 1) * sizeof(int));
    float* S         = (float*)alloc((size_t)NH * NR * sizeof(float));
    float* tsum      = (float*)alloc((size_t)NT * sizeof(float));
    float* rsum      = (float*)alloc((size_t)NR * sizeof(float));
    (void)ws_size;

    int sBlocks = (NH * NR + 255) / 256;
    int tBlocks = (NT + 3) / 4;
    int rBlocks = (NR + 3) / 4;
    precompute_k<<<sBlocks + tBlocks + rBlocks, 256, 0, stream>>>(
        Hv, Rv, Tv, S, tsum, rsum, NH, NR, NT, sBlocks, tBlocks);

    seg_bounds_k<<<(B + 1 + 255) / 256, 256, 0, stream>>>(eseg, E, B, seg_start);

    main_k<<<(B + 3) / 4, 256, 0, stream>>>(
        h, erel, etail, S, tsum, rsum, seg_start, (float*)d_out, B, NR);
}

// Round 2
// 22.952 us; speedup vs baseline: 1.5411x; 1.5411x over previous
//
#include <hip/hip_runtime.h>
#include <math.h>

// ---------------------------------------------------------------------------
// B=32768 segments, E=1M sorted edges, DIM=64.
//   score[e]   = dot(H_emb[h[seg[e]]], R_emb[rel[e]])  -> table S[h][rel]
//   w          = segment_softmax(score)
//   contrib[e] = w[e] * (tsum[tail[e]] - rsum[rel[e]])
//   out[s][:]  = broadcast(segment_sum(contrib))
//
// Kernel 1 (setup_k, block-range partitioned jobs):
//   job0: seg_start scatter from sorted edge_seg (coalesced, no binary search)
//   job1: S table via LDS-transposed R (stride-1 LDS reads, no L1 gather)
//   job2: tsum rows   job3: rsum rows
// Kernel 2 (main_k): 32 lanes per segment, online softmax + xor-merge.
// ---------------------------------------------------------------------------

__global__ __launch_bounds__(256) void setup_k(
    const int* __restrict__ seg, int E, int B, int* __restrict__ seg_start,
    const float* __restrict__ H, const float* __restrict__ R,
    const float* __restrict__ T,
    float* __restrict__ S, float* __restrict__ tsum, float* __restrict__ rsum,
    int NH, int NR, int NT, int eBlocks, int sBlocks, int tBlocks)
{
    int b = blockIdx.x;

    if (b < eBlocks) {
        // --- job0: segment boundaries from sorted seg[] ---
        int e = b * 256 + threadIdx.x;
        if (e < E) {
            int cur = seg[e];
            if (e == 0) {
                for (int s = 0; s <= cur; ++s) seg_start[s] = 0;
            } else {
                int prev = seg[e - 1];
                for (int s = prev + 1; s <= cur; ++s) seg_start[s] = e;
            }
            if (e == E - 1) {
                for (int s = cur + 1; s <= B; ++s) seg_start[s] = E;
            }
        }
        return;
    }
    b -= eBlocks;

    if (b < sBlocks) {
        // --- job1: S[i*NR+r] = dot64(H[i], R[r]) with R transposed in LDS ---
        __shared__ float Rt[64 * 64];           // [d][r], NR<=64
        for (int t = threadIdx.x; t < NR * 64; t += 256) {
            int r = t >> 6, d = t & 63;
            Rt[d * NR + r] = R[t];
        }
        __syncthreads();

        int idx = b * 256 + threadIdx.x;
        if (idx < NH * NR) {
            int i = idx / NR;
            int r = idx - i * NR;
            const float4* h4 = (const float4*)(H + (size_t)i * 64);
            float acc = 0.f;
            #pragma unroll
            for (int q = 0; q < 16; ++q) {
                float4 hv = h4[q];
                int d = q * 4;
                acc = fmaf(hv.x, Rt[(d + 0) * NR + r], acc);
                acc = fmaf(hv.y, Rt[(d + 1) * NR + r], acc);
                acc = fmaf(hv.z, Rt[(d + 2) * NR + r], acc);
                acc = fmaf(hv.w, Rt[(d + 3) * NR + r], acc);
            }
            S[idx] = acc;
        }
        return;
    }
    b -= sBlocks;

    int lane = threadIdx.x & 63;
    if (b < tBlocks) {
        // --- job2: tsum[t] = sum_d T[t][d] ---
        int row = b * 4 + (threadIdx.x >> 6);
        if (row < NT) {
            float v = T[(size_t)row * 64 + lane];
            #pragma unroll
            for (int off = 32; off; off >>= 1) v += __shfl_xor(v, off, 64);
            if (lane == 0) tsum[row] = v;
        }
        return;
    }
    b -= tBlocks;

    // --- job3: rsum[r] = sum_d R[r][d] ---
    {
        int row = b * 4 + (threadIdx.x >> 6);
        if (row < NR) {
            float v = R[(size_t)row * 64 + lane];
            #pragma unroll
            for (int off = 32; off; off >>= 1) v += __shfl_xor(v, off, 64);
            if (lane == 0) rsum[row] = v;
        }
    }
}

// One 32-lane group per segment (2 segments per wave).
__global__ __launch_bounds__(256) void main_k(
    const int* __restrict__ h,
    const int* __restrict__ edge_rel, const int* __restrict__ edge_tail,
    const float* __restrict__ S, const float* __restrict__ tsum,
    const float* __restrict__ rsum, const int* __restrict__ seg_start,
    float* __restrict__ out, int B, int NR)
{
    int grp = blockIdx.x * 8 + (threadIdx.x >> 5);   // 8 groups of 32 per block
    int sub = threadIdx.x & 31;
    if (grp >= B) return;

    int lo = seg_start[grp];
    int hi = seg_start[grp + 1];
    int hh = h[grp];
    const float* Srow = S + (size_t)hh * NR;

    // Per-lane online softmax accumulation over strided edges.
    float m = -INFINITY, se = 0.f, sec = 0.f;
    for (int e = lo + sub; e < hi; e += 32) {
        int rel = edge_rel[e];
        int tl  = edge_tail[e];
        float sc = Srow[rel];
        float c  = tsum[tl] - rsum[rel];
        if (sc > m) {
            float f = __expf(m - sc);   // m=-inf -> f=0 on first hit
            se *= f; sec *= f; m = sc;
        }
        float w = __expf(sc - m);
        se += w; sec = fmaf(w, c, sec);
    }

    // 5-step xor merge within the 32-lane group (empty-lane guard avoids NaN).
    #pragma unroll
    for (int off = 16; off; off >>= 1) {
        float m2   = __shfl_xor(m, off, 64);
        float se2  = __shfl_xor(se, off, 64);
        float sec2 = __shfl_xor(sec, off, 64);
        float M  = fmaxf(m, m2);
        float a  = (se  > 0.f) ? __expf(m  - M) : 0.f;
        float b2 = (se2 > 0.f) ? __expf(m2 - M) : 0.f;
        se  = se * a + se2 * b2;
        sec = sec * a + sec2 * b2;
        m = M;
    }

    float vc = (se > 0.f) ? (sec / se) : 0.f;
    float2 v2 = make_float2(vc, vc);
    *(float2*)(out + (size_t)grp * 64 + sub * 2) = v2;   // coalesced
}

extern "C" void kernel_launch(void* const* d_in, const int* in_sizes, int n_in,
                              void* d_out, int out_size, void* d_ws, size_t ws_size,
                              hipStream_t stream)
{
    const int*   h     = (const int*)d_in[0];
    const int*   eseg  = (const int*)d_in[1];
    const int*   erel  = (const int*)d_in[2];
    const int*   etail = (const int*)d_in[3];
    const float* Hv    = (const float*)d_in[4];
    const float* Rv    = (const float*)d_in[5];
    const float* Tv    = (const float*)d_in[6];

    int B  = in_sizes[0];
    int E  = in_sizes[1];
    int NH = in_sizes[4] / 64;
    int NR = in_sizes[5] / 64;
    int NT = in_sizes[6] / 64;

    // Workspace carve-out (256B aligned): seg_start | S | tsum | rsum (~1.1 MB)
    char*  ws  = (char*)d_ws;
    size_t off = 0;
    auto alloc = [&](size_t bytes) -> void* {
        void* p = ws + off;
        off = (off + bytes + 255) & ~(size_t)255;
        return p;
    };
    int*   seg_start = (int*)  alloc((size_t)(B + 1) * sizeof(int));
    float* S         = (float*)alloc((size_t)NH * NR * sizeof(float));
    float* tsum      = (float*)alloc((size_t)NT * sizeof(float));
    float* rsum      = (float*)alloc((size_t)NR * sizeof(float));
    (void)ws_size;

    int eBlocks = (E + 255) / 256;
    int sBlocks = (NH * NR + 255) / 256;
    int tBlocks = (NT + 3) / 4;
    int rBlocks = (NR + 3) / 4;
    setup_k<<<eBlocks + sBlocks + tBlocks + rBlocks, 256, 0, stream>>>(
        eseg, E, B, seg_start, Hv, Rv, Tv, S, tsum, rsum,
        NH, NR, NT, eBlocks, sBlocks, tBlocks);

    main_k<<<(B + 7) / 8, 256, 0, stream>>>(
        h, erel, etail, S, tsum, rsum, seg_start, (float*)d_out, B, NR);
}